// Round 4
// baseline (217.385 us; speedup 1.0000x reference)
//
#include <hip/hip_runtime.h>
#include <hip/hip_fp16.h>
#include <math.h>

#define NODE_DIM 128
#define EDGE_DIM 128
#define N_RADIAL 16
#define MAXZ     100
#define BLOCK    512
#define GROUPS   (BLOCK / 32)   // 16 edges in flight per block-iteration

// ---------------------------------------------------------------------------
// Precompute: t1[r][d] = sum_k embed[r][k]*edge_w[k][d] + edge_b[d]   (fp16)
//             t2[r][d] = sum_k embed[r][k]*edge_w[128+k][d]           (fp16)
// tH[0..MAXZ*128) = t1 rows, tH[MAXZ*128..) = t2 rows.
// ---------------------------------------------------------------------------
__global__ void precompute_node_tables(const float* __restrict__ embed_table,
                                       const float* __restrict__ edge_w,
                                       const float* __restrict__ edge_b,
                                       __half* __restrict__ tH) {
    const int r = blockIdx.x;
    const int d = threadIdx.x;
    float s1 = edge_b[d];
    float s2 = 0.0f;
    const float* er = embed_table + (long)r * NODE_DIM;
#pragma unroll 8
    for (int k = 0; k < NODE_DIM; ++k) {
        const float e = er[k];
        s1 += e * edge_w[(long)k * EDGE_DIM + d];
        s2 += e * edge_w[(long)(NODE_DIM + k) * EDGE_DIM + d];
    }
    tH[(long)r * EDGE_DIM + d]          = __float2half(s1);
    tH[(long)(MAXZ + r) * EDGE_DIM + d] = __float2half(s2);
}

// ---------------------------------------------------------------------------
// Precompute: w3c[r][d] = sum_k rbf_w[r][k] * edge_w[256+k][d]   (16x128 fp32)
// ---------------------------------------------------------------------------
__global__ void precompute_rbf_mat(const float* __restrict__ rbf_w,
                                   const float* __restrict__ edge_w,
                                   float* __restrict__ w3c) {
    const int r = blockIdx.x;   // 0..15
    const int d = threadIdx.x;  // 0..127
    float s = 0.0f;
    const float* rr = rbf_w + (long)r * EDGE_DIM;
#pragma unroll 8
    for (int k = 0; k < EDGE_DIM; ++k)
        s += rr[k] * edge_w[(long)(2 * NODE_DIM + k) * EDGE_DIM + d];
    w3c[(long)r * EDGE_DIM + d] = s;
}

// ---------------------------------------------------------------------------
// Main kernel: fp16 tables resident in LDS; everything else streams from
// global with a 3-stage register pipeline per 32-lane group.  No in-loop
// barriers.  Each group owns one edge per iteration; each lane one float4
// of the 128-wide output row.
// ---------------------------------------------------------------------------
__global__ void __launch_bounds__(BLOCK, 4) edge_embed_kernel(
        const int*    __restrict__ z,
        const float*  __restrict__ rbf,
        const int*    __restrict__ idx_i,
        const int*    __restrict__ idx_j,
        const __half* __restrict__ tH,
        const float*  __restrict__ w3c,
        float* __restrict__ out,
        int n_edges) {
    __shared__ __half sTab[2 * MAXZ * EDGE_DIM];       // 51200 B

    const int tid = threadIdx.x;
    const int sub = tid & 31;      // which float4 of the row
    const int grp = tid >> 5;      // 0..15

    // this lane's 16x4 slice of w3c -> 64 VGPRs (L1-broadcast reads)
    float4 w[N_RADIAL];
#pragma unroll
    for (int r = 0; r < N_RADIAL; ++r)
        w[r] = *reinterpret_cast<const float4*>(&w3c[r * EDGE_DIM + (sub << 2)]);

    // cooperative copy of both tables into LDS (3200 uint4)
    {
        const uint4* src = reinterpret_cast<const uint4*>(tH);
        uint4*       dst = reinterpret_cast<uint4*>(sTab);
        for (int i = tid; i < (2 * MAXZ * EDGE_DIM) / 8; i += BLOCK)
            dst[i] = src[i];
    }
    __syncthreads();

    const int nb  = gridDim.x;
    const int bid = blockIdx.x;
    const int elo = (int)(((long)bid * n_edges) / nb);
    const int ehi = (int)(((long)(bid + 1) * n_edges) / nb);

    const float4* rbf4 = reinterpret_cast<const float4*>(rbf);
    const int emax = n_edges - 1;

    int e = elo + grp;

    // ---- prologue: fill the 3-stage pipeline ----
    const int eA = e < emax ? e : emax;
    int       eB = e + GROUPS; eB = eB < emax ? eB : emax;
    int ijB = idx_j[eB], iiB = idx_i[eB];              // idx for e+16
    int zjC = z[idx_j[eA]], ziC = z[idx_i[eA]];        // z for e (serial, once)
    float4 r0 = rbf4[(long)eA * 4 + 0];
    float4 r1 = rbf4[(long)eA * 4 + 1];
    float4 r2 = rbf4[(long)eA * 4 + 2];
    float4 r3 = rbf4[(long)eA * 4 + 3];

    for (; e < ehi; e += GROUPS) {
        // stage 1: issue idx loads for e+32
        int eN = e + 2 * GROUPS; eN = eN < emax ? eN : emax;
        const int ijN = idx_j[eN], iiN = idx_i[eN];
        // stage 2: issue z + rbf loads for e+16 (uses idx loaded last iter)
        const int zjN = z[ijB], ziN = z[iiB];
        int eB1 = e + GROUPS; eB1 = eB1 < emax ? eB1 : emax;
        const float4 n0 = rbf4[(long)eB1 * 4 + 0];
        const float4 n1 = rbf4[(long)eB1 * 4 + 1];
        const float4 n2 = rbf4[(long)eB1 * 4 + 2];
        const float4 n3 = rbf4[(long)eB1 * 4 + 3];

        // stage 3: compute edge e from registers + LDS table reads
        const uint2 uj = *reinterpret_cast<const uint2*>(
            &sTab[zjC * EDGE_DIM + (sub << 2)]);
        const uint2 ui = *reinterpret_cast<const uint2*>(
            &sTab[(MAXZ + ziC) * EDGE_DIM + (sub << 2)]);
        const __half2 h0 = __hadd2(*reinterpret_cast<const __half2*>(&uj.x),
                                   *reinterpret_cast<const __half2*>(&ui.x));
        const __half2 h1 = __hadd2(*reinterpret_cast<const __half2*>(&uj.y),
                                   *reinterpret_cast<const __half2*>(&ui.y));
        const float2 f0 = __half22float2(h0);
        const float2 f1 = __half22float2(h1);
        float4 acc = make_float4(f0.x, f0.y, f1.x, f1.y);

#define RBF_FMA(RV, W0, W1, W2, W3)                    \
        acc.x += RV.x * W0.x; acc.y += RV.x * W0.y;    \
        acc.z += RV.x * W0.z; acc.w += RV.x * W0.w;    \
        acc.x += RV.y * W1.x; acc.y += RV.y * W1.y;    \
        acc.z += RV.y * W1.z; acc.w += RV.y * W1.w;    \
        acc.x += RV.z * W2.x; acc.y += RV.z * W2.y;    \
        acc.z += RV.z * W2.z; acc.w += RV.z * W2.w;    \
        acc.x += RV.w * W3.x; acc.y += RV.w * W3.y;    \
        acc.z += RV.w * W3.z; acc.w += RV.w * W3.w;

        RBF_FMA(r0, w[0],  w[1],  w[2],  w[3])
        RBF_FMA(r1, w[4],  w[5],  w[6],  w[7])
        RBF_FMA(r2, w[8],  w[9],  w[10], w[11])
        RBF_FMA(r3, w[12], w[13], w[14], w[15])
#undef RBF_FMA

        // swish: x * sigmoid(x), fast rcp (|rel err| ~1e-6, threshold 0.09)
        float4 o;
        o.x = acc.x * __builtin_amdgcn_rcpf(1.0f + __expf(-acc.x));
        o.y = acc.y * __builtin_amdgcn_rcpf(1.0f + __expf(-acc.y));
        o.z = acc.z * __builtin_amdgcn_rcpf(1.0f + __expf(-acc.z));
        o.w = acc.w * __builtin_amdgcn_rcpf(1.0f + __expf(-acc.w));

        *reinterpret_cast<float4*>(&out[(size_t)e * EDGE_DIM + (sub << 2)]) = o;

        // rotate pipeline
        ijB = ijN; iiB = iiN;
        zjC = zjN; ziC = ziN;
        r0 = n0; r1 = n1; r2 = n2; r3 = n3;
    }
}

extern "C" void kernel_launch(void* const* d_in, const int* in_sizes, int n_in,
                              void* d_out, int out_size, void* d_ws, size_t ws_size,
                              hipStream_t stream) {
    const int*   zp          = (const int*)  d_in[0];
    const float* rbf         = (const float*)d_in[1];
    const int*   idx_i       = (const int*)  d_in[2];
    const int*   idx_j       = (const int*)  d_in[3];
    const float* embed_table = (const float*)d_in[4];
    const float* rbf_w       = (const float*)d_in[5];
    const float* edge_w      = (const float*)d_in[6];
    const float* edge_b      = (const float*)d_in[7];

    int max_z = in_sizes[4] / NODE_DIM;           // 100
    if (max_z > MAXZ) max_z = MAXZ;
    const int n_edges = in_sizes[2];              // 800000

    __half* tH  = (__half*)d_ws;                               // 2*MAXZ*128 fp16
    float*  w3c = (float*)((char*)d_ws + 2 * MAXZ * EDGE_DIM * sizeof(__half));
    float*  out = (float*)d_out;

    precompute_node_tables<<<max_z, EDGE_DIM, 0, stream>>>(embed_table, edge_w,
                                                           edge_b, tH);
    precompute_rbf_mat<<<N_RADIAL, EDGE_DIM, 0, stream>>>(rbf_w, edge_w, w3c);

    // persistent grid: 2 blocks per CU, contiguous edge ranges
    int grid = 512;
    if (grid > n_edges) grid = n_edges;
    edge_embed_kernel<<<grid, BLOCK, 0, stream>>>(zp, rbf, idx_i, idx_j,
                                                  tH, w3c, out, n_edges);
}

// Round 6
// 133.371 us; speedup vs baseline: 1.6299x; 1.6299x over previous
//
#include <hip/hip_runtime.h>
#include <hip/hip_fp16.h>
#include <math.h>

#define NODE_DIM 128
#define EDGE_DIM 128
#define N_RADIAL 16
#define MAXZ     100
#define CHUNK    128          // edges per chunk (CHUNK*16 floats = BLOCK float4)
#define BLOCK    512          // threads per block (8 waves)

typedef float  fx4 __attribute__((ext_vector_type(4)));

// ---------------------------------------------------------------------------
// Precompute: t1[r][d] = sum_k embed[r][k]*edge_w[k][d] + edge_b[d]   (fp16)
//             t2[r][d] = sum_k embed[r][k]*edge_w[128+k][d]           (fp16)
// ---------------------------------------------------------------------------
__global__ void precompute_node_tables(const float* __restrict__ embed_table,
                                       const float* __restrict__ edge_w,
                                       const float* __restrict__ edge_b,
                                       __half* __restrict__ tH) {
    const int r = blockIdx.x;
    const int d = threadIdx.x;
    float s1 = edge_b[d];
    float s2 = 0.0f;
    const float* er = embed_table + (long)r * NODE_DIM;
#pragma unroll 8
    for (int k = 0; k < NODE_DIM; ++k) {
        const float e = er[k];
        s1 += e * edge_w[(long)k * EDGE_DIM + d];
        s2 += e * edge_w[(long)(NODE_DIM + k) * EDGE_DIM + d];
    }
    tH[(long)r * EDGE_DIM + d]          = __float2half(s1);
    tH[(long)(MAXZ + r) * EDGE_DIM + d] = __float2half(s2);
}

// ---------------------------------------------------------------------------
// Precompute: w3c[r][d] = sum_k rbf_w[r][k] * edge_w[256+k][d]   (16x128 fp32)
// ---------------------------------------------------------------------------
__global__ void precompute_rbf_mat(const float* __restrict__ rbf_w,
                                   const float* __restrict__ edge_w,
                                   float* __restrict__ w3c) {
    const int r = blockIdx.x;   // 0..15
    const int d = threadIdx.x;  // 0..127
    float s = 0.0f;
    const float* rr = rbf_w + (long)r * EDGE_DIM;
#pragma unroll 8
    for (int k = 0; k < EDGE_DIM; ++k)
        s += rr[k] * edge_w[(long)(2 * NODE_DIM + k) * EDGE_DIM + d];
    w3c[(long)r * EDGE_DIM + d] = s;
}

// ---------------------------------------------------------------------------
// Precompute per-edge packed z indices: zpair[e] = zj | (zi << 16).
// Moves the scattered 2-hop idx->z chain out of the hot kernel.
// ---------------------------------------------------------------------------
__global__ void precompute_zpair(const int* __restrict__ z,
                                 const int* __restrict__ idx_i,
                                 const int* __restrict__ idx_j,
                                 int* __restrict__ zpair,
                                 int n_edges) {
    const int e = blockIdx.x * blockDim.x + threadIdx.x;
    if (e < n_edges) {
        const int zj = z[idx_j[e]];
        const int zi = z[idx_i[e]];
        zpair[e] = (zj & 0xffff) | (zi << 16);
    }
}

// ---------------------------------------------------------------------------
// Main kernel (R3 structure): fp16 tables in LDS, double-buffered staging of
// rbf + zpair with one barrier per chunk; rcp-swish; non-temporal streaming.
// ---------------------------------------------------------------------------
__global__ void __launch_bounds__(BLOCK, 4) edge_embed_kernel(
        const int*    __restrict__ z,
        const float*  __restrict__ rbf,
        const int*    __restrict__ idx_i,
        const int*    __restrict__ idx_j,
        const __half* __restrict__ tH,
        const float*  __restrict__ w3c,
        const int*    __restrict__ zpair,
        int use_zpair,
        float* __restrict__ out,
        int n_edges, int nch) {
    __shared__ __half sTab[2 * MAXZ * EDGE_DIM];       // 51200 B
    __shared__ float  sRbf[2][CHUNK * N_RADIAL];       // 16384 B
    __shared__ int    sZ[2][CHUNK];                    // 1024 B

    const int tid = threadIdx.x;
    const int sub = tid & 31;     // float4 column of the 128-wide row
    const int grp = tid >> 5;     // 0..15: edge-group

    // this lane's 16x4 slice of w3c -> 64 VGPRs
    float4 w[N_RADIAL];
#pragma unroll
    for (int r = 0; r < N_RADIAL; ++r)
        w[r] = *reinterpret_cast<const float4*>(&w3c[r * EDGE_DIM + (sub << 2)]);

    // cooperative copy of both tables into LDS (3200 uint4 = 51.2 KB)
    {
        const uint4* src = reinterpret_cast<const uint4*>(tH);
        uint4*       dst = reinterpret_cast<uint4*>(sTab);
        for (int i = tid; i < (2 * MAXZ * EDGE_DIM) / 8; i += BLOCK)
            dst[i] = src[i];
    }

    const int bid = blockIdx.x;
    const int nb  = gridDim.x;
    const int clo = (int)(((long)bid * nch) / nb);
    const int chi = (int)(((long)(bid + 1) * nch) / nb);
    if (clo >= chi) return;   // uniform per block

    const fx4* rbf4 = reinterpret_cast<const fx4*>(rbf);
    const long nf4 = ((long)n_edges * N_RADIAL) >> 2;

    // ---- prologue: stage chunk clo into buffer 0 ----
    {
        if (tid < CHUNK) {
            int e = clo * CHUNK + tid;
            if (e >= n_edges) e = n_edges - 1;
            int zp;
            if (use_zpair) zp = zpair[e];
            else           zp = (z[idx_j[e]] & 0xffff) | (z[idx_i[e]] << 16);
            sZ[0][tid] = zp;
        }
        const long f4 = (long)clo * BLOCK + tid;
        fx4 rv = (fx4)0.0f;
        if (f4 < nf4) rv = __builtin_nontemporal_load(rbf4 + f4);
        reinterpret_cast<fx4*>(&sRbf[0][0])[tid] = rv;
    }
    __syncthreads();

    for (int c = clo; c < chi; ++c) {
        const int  par  = (c - clo) & 1;
        const bool has1 = (c + 1) < chi;

        // ---- issue next-chunk loads (held in regs until after compute) ----
        int zn = 0;
        fx4 rn = (fx4)0.0f;
        if (has1) {
            if (tid < CHUNK) {
                int e = (c + 1) * CHUNK + tid;
                if (e >= n_edges) e = n_edges - 1;
                if (use_zpair) zn = zpair[e];
                else           zn = (z[idx_j[e]] & 0xffff) | (z[idx_i[e]] << 16);
            }
            const long f4 = (long)(c + 1) * BLOCK + tid;
            if (f4 < nf4) rn = __builtin_nontemporal_load(rbf4 + f4);
        }

        // ---- compute chunk c from buffers[par] ----
        const int ebase = c * CHUNK;
#pragma unroll
        for (int s = 0; s < 8; ++s) {
            const int el = (s << 4) | grp;
            const int e  = ebase + el;
            const int zp = sZ[par][el];
            const int zj = zp & 0xffff;
            const int zi = zp >> 16;

            const uint2 uj = *reinterpret_cast<const uint2*>(
                &sTab[zj * EDGE_DIM + (sub << 2)]);
            const uint2 ui = *reinterpret_cast<const uint2*>(
                &sTab[(MAXZ + zi) * EDGE_DIM + (sub << 2)]);
            const __half2 h0 = __hadd2(*reinterpret_cast<const __half2*>(&uj.x),
                                       *reinterpret_cast<const __half2*>(&ui.x));
            const __half2 h1 = __hadd2(*reinterpret_cast<const __half2*>(&uj.y),
                                       *reinterpret_cast<const __half2*>(&ui.y));
            const float2 f0 = __half22float2(h0);
            const float2 f1 = __half22float2(h1);
            float4 acc = make_float4(f0.x, f0.y, f1.x, f1.y);

            const float4* rb =
                reinterpret_cast<const float4*>(&sRbf[par][el * N_RADIAL]);
#pragma unroll
            for (int q = 0; q < 4; ++q) {
                const float4 rq = rb[q];
                acc.x += rq.x * w[q * 4 + 0].x;
                acc.y += rq.x * w[q * 4 + 0].y;
                acc.z += rq.x * w[q * 4 + 0].z;
                acc.w += rq.x * w[q * 4 + 0].w;

                acc.x += rq.y * w[q * 4 + 1].x;
                acc.y += rq.y * w[q * 4 + 1].y;
                acc.z += rq.y * w[q * 4 + 1].z;
                acc.w += rq.y * w[q * 4 + 1].w;

                acc.x += rq.z * w[q * 4 + 2].x;
                acc.y += rq.z * w[q * 4 + 2].y;
                acc.z += rq.z * w[q * 4 + 2].z;
                acc.w += rq.z * w[q * 4 + 2].w;

                acc.x += rq.w * w[q * 4 + 3].x;
                acc.y += rq.w * w[q * 4 + 3].y;
                acc.z += rq.w * w[q * 4 + 3].z;
                acc.w += rq.w * w[q * 4 + 3].w;
            }

            // swish via fast rcp (rel err ~1e-6 vs threshold 0.09)
            fx4 o;
            o.x = acc.x * __builtin_amdgcn_rcpf(1.0f + __expf(-acc.x));
            o.y = acc.y * __builtin_amdgcn_rcpf(1.0f + __expf(-acc.y));
            o.z = acc.z * __builtin_amdgcn_rcpf(1.0f + __expf(-acc.z));
            o.w = acc.w * __builtin_amdgcn_rcpf(1.0f + __expf(-acc.w));

            if (e < n_edges)
                __builtin_nontemporal_store(o, reinterpret_cast<fx4*>(
                    &out[(size_t)e * EDGE_DIM + (sub << 2)]));
        }

        // ---- write staged next-chunk data into the other buffer ----
        if (has1) {
            const int pn = par ^ 1;
            reinterpret_cast<fx4*>(&sRbf[pn][0])[tid] = rn;
            if (tid < CHUNK) sZ[pn][tid] = zn;
        }
        __syncthreads();
    }
}

extern "C" void kernel_launch(void* const* d_in, const int* in_sizes, int n_in,
                              void* d_out, int out_size, void* d_ws, size_t ws_size,
                              hipStream_t stream) {
    const int*   zp          = (const int*)  d_in[0];
    const float* rbf         = (const float*)d_in[1];
    const int*   idx_i       = (const int*)  d_in[2];
    const int*   idx_j       = (const int*)  d_in[3];
    const float* embed_table = (const float*)d_in[4];
    const float* rbf_w       = (const float*)d_in[5];
    const float* edge_w      = (const float*)d_in[6];
    const float* edge_b      = (const float*)d_in[7];

    int max_z = in_sizes[4] / NODE_DIM;           // 100
    if (max_z > MAXZ) max_z = MAXZ;
    const int n_edges = in_sizes[2];              // 800000

    const size_t tab_bytes = (size_t)2 * MAXZ * EDGE_DIM * sizeof(__half); // 51200
    const size_t w3c_bytes = (size_t)N_RADIAL * EDGE_DIM * sizeof(float);  // 8192
    __half* tH    = (__half*)d_ws;
    float*  w3c   = (float*)((char*)d_ws + tab_bytes);
    int*    zpair = (int*)  ((char*)d_ws + tab_bytes + w3c_bytes);
    const int use_zpair =
        (ws_size >= tab_bytes + w3c_bytes + (size_t)n_edges * sizeof(int)) ? 1 : 0;
    float* out = (float*)d_out;

    precompute_node_tables<<<max_z, EDGE_DIM, 0, stream>>>(embed_table, edge_w,
                                                           edge_b, tH);
    precompute_rbf_mat<<<N_RADIAL, EDGE_DIM, 0, stream>>>(rbf_w, edge_w, w3c);
    if (use_zpair)
        precompute_zpair<<<(n_edges + 255) / 256, 256, 0, stream>>>(
            zp, idx_i, idx_j, zpair, n_edges);

    const int nch = (n_edges + CHUNK - 1) / CHUNK;   // 6250
    int grid = nch < 512 ? nch : 512;                // 2 blocks/CU persistent
    edge_embed_kernel<<<grid, BLOCK, 0, stream>>>(zp, rbf, idx_i, idx_j,
                                                  tH, w3c, zpair, use_zpair,
                                                  out, n_edges, nch);
}

// Round 7
// 129.704 us; speedup vs baseline: 1.6760x; 1.0283x over previous
//
#include <hip/hip_runtime.h>
#include <hip/hip_fp16.h>

#define NODE_DIM 128
#define EDGE_DIM 128
#define N_RADIAL 16
#define MAXZ     100
#define BLOCK    512
#define NWAVE    (BLOCK / 64)
#define MC       16            // edges per wave-private mini-chunk

typedef float fx4 __attribute__((ext_vector_type(4)));

// ---------------------------------------------------------------------------
// Fused precompute: blocks [0,max_z) -> fp16 node tables; [max_z,max_z+16) ->
// w3c[r][d] = sum_k rbf_w[r][k] * edge_w[256+k][d].
// ---------------------------------------------------------------------------
__global__ void precompute_tables(const float* __restrict__ embed_table,
                                  const float* __restrict__ edge_w,
                                  const float* __restrict__ edge_b,
                                  const float* __restrict__ rbf_w,
                                  __half* __restrict__ tH,
                                  float* __restrict__ w3c,
                                  int max_z) {
    const int d = threadIdx.x;
    if ((int)blockIdx.x < max_z) {
        const int r = blockIdx.x;
        float s1 = edge_b[d];
        float s2 = 0.0f;
        const float* er = embed_table + (long)r * NODE_DIM;
#pragma unroll 8
        for (int k = 0; k < NODE_DIM; ++k) {
            const float e = er[k];
            s1 += e * edge_w[(long)k * EDGE_DIM + d];
            s2 += e * edge_w[(long)(NODE_DIM + k) * EDGE_DIM + d];
        }
        tH[(long)r * EDGE_DIM + d]          = __float2half(s1);
        tH[(long)(MAXZ + r) * EDGE_DIM + d] = __float2half(s2);
    } else {
        const int r = blockIdx.x - max_z;     // 0..15
        float s = 0.0f;
        const float* rr = rbf_w + (long)r * EDGE_DIM;
#pragma unroll 8
        for (int k = 0; k < EDGE_DIM; ++k)
            s += rr[k] * edge_w[(long)(2 * NODE_DIM + k) * EDGE_DIM + d];
        w3c[(long)r * EDGE_DIM + d] = s;
    }
}

// ---------------------------------------------------------------------------
// Precompute per-edge packed z indices: zpair[e] = zj | (zi << 16).
// ---------------------------------------------------------------------------
__global__ void precompute_zpair(const int* __restrict__ z,
                                 const int* __restrict__ idx_i,
                                 const int* __restrict__ idx_j,
                                 int* __restrict__ zpair,
                                 int n_edges) {
    const int e = blockIdx.x * blockDim.x + threadIdx.x;
    if (e < n_edges) {
        const int zj = z[idx_j[e]];
        const int zi = z[idx_i[e]];
        zpair[e] = (zj & 0xffff) | (zi << 16);
    }
}

// ---------------------------------------------------------------------------
// Main kernel: fp16 tables in LDS (one barrier after load, none in loop).
// Each WAVE free-runs over contiguous 16-edge mini-chunks with a private
// LDS double-buffer for rbf + zpair.  Loads for chunk m+1 are issued before
// chunk m's compute; the pre-ds_write vmcnt wait therefore never waits on
// the compute stores.  Stores are normal (L2-acked); nt only on rbf loads.
// ---------------------------------------------------------------------------
__global__ void __launch_bounds__(BLOCK, 4) edge_embed_kernel(
        const float*  __restrict__ rbf,
        const __half* __restrict__ tH,
        const float*  __restrict__ w3c,
        const int*    __restrict__ zpair,
        const int*    __restrict__ z,
        const int*    __restrict__ idx_i,
        const int*    __restrict__ idx_j,
        int use_zpair,
        float* __restrict__ out,
        int n_edges) {
    __shared__ __half sTab[2 * MAXZ * EDGE_DIM];              // 51200 B
    __shared__ float  sRbf[NWAVE * 2 * MC * N_RADIAL];        // 16384 B
    __shared__ int    sZ[NWAVE * 2 * MC];                     // 1024 B

    const int tid  = threadIdx.x;
    const int lane = tid & 63;
    const int wv   = tid >> 6;          // 0..7
    const int sub  = tid & 31;          // float4 column of the 128-wide row
    const int half = (lane >> 5) & 1;   // which of the 2 edges this step

    // this lane's 16x4 slice of w3c -> 64 VGPRs
    float4 w[N_RADIAL];
#pragma unroll
    for (int r = 0; r < N_RADIAL; ++r)
        w[r] = *reinterpret_cast<const float4*>(&w3c[r * EDGE_DIM + (sub << 2)]);

    // cooperative copy of both tables into LDS (3200 uint4 = 51.2 KB)
    {
        const uint4* src = reinterpret_cast<const uint4*>(tH);
        uint4*       dst = reinterpret_cast<uint4*>(sTab);
        for (int i = tid; i < (2 * MAXZ * EDGE_DIM) / 8; i += BLOCK)
            dst[i] = src[i];
    }
    __syncthreads();   // the only block-wide barrier

    // wave-private LDS bases
    float* rbW = &sRbf[wv * (2 * MC * N_RADIAL)];
    int*   zW  = &sZ[wv * (2 * MC)];

    // contiguous mini-chunk range for this wave
    const int W   = gridDim.x * NWAVE;
    const int gw  = blockIdx.x * NWAVE + wv;
    const int nmc = (n_edges + MC - 1) / MC;
    const int mlo = (int)(((long)gw * nmc) / W);
    const int mhi = (int)(((long)(gw + 1) * nmc) / W);
    if (mlo >= mhi) return;

    const fx4* rbf4 = reinterpret_cast<const fx4*>(rbf);
    const int  emax = n_edges - 1;
    const int  eqtr = lane & 3;         // which float4 of the rbf row this lane stages
    const int  eoff = lane >> 2;        // which of the 16 edges this lane stages

    // ---- prologue: stage mini-chunk mlo into buffer 0 ----
    {
        int e = mlo * MC + eoff; if (e > emax) e = emax;
        const fx4 rv = __builtin_nontemporal_load(rbf4 + (long)e * 4 + eqtr);
        *reinterpret_cast<fx4*>(rbW + eoff * N_RADIAL + (eqtr << 2)) = rv;
        int ze = mlo * MC + (lane & (MC - 1)); if (ze > emax) ze = emax;
        int zv;
        if (use_zpair) zv = zpair[ze];
        else           zv = (z[idx_j[ze]] & 0xffff) | (z[idx_i[ze]] << 16);
        if (lane < MC) zW[lane] = zv;
    }

    for (int m = mlo; m < mhi; ++m) {
        const int  p    = (m - mlo) & 1;
        const bool hasn = (m + 1) < mhi;

        // ---- issue next-chunk loads first (held in regs until after compute)
        fx4 rn = (fx4)0.0f;
        int zn = 0;
        if (hasn) {
            int e = (m + 1) * MC + eoff; if (e > emax) e = emax;
            rn = __builtin_nontemporal_load(rbf4 + (long)e * 4 + eqtr);
            int ze = (m + 1) * MC + (lane & (MC - 1)); if (ze > emax) ze = emax;
            if (use_zpair) zn = zpair[ze];
            else           zn = (z[idx_j[ze]] & 0xffff) | (z[idx_i[ze]] << 16);
        }

        // ---- compute the 16 edges of chunk m from buffer p ----
        const float* rbB = rbW + p * (MC * N_RADIAL);
        const int*   zB  = zW  + p * MC;
        const int ebase  = m * MC;
#pragma unroll
        for (int s = 0; s < MC / 2; ++s) {
            const int el = (s << 1) | half;
            const int e  = ebase + el;
            const int zp = zB[el];                       // LDS broadcast
            const int zj = zp & 0xffff;
            const int zi = zp >> 16;

            const uint2 uj = *reinterpret_cast<const uint2*>(
                &sTab[zj * EDGE_DIM + (sub << 2)]);
            const uint2 ui = *reinterpret_cast<const uint2*>(
                &sTab[(MAXZ + zi) * EDGE_DIM + (sub << 2)]);
            const __half2 h0 = __hadd2(*reinterpret_cast<const __half2*>(&uj.x),
                                       *reinterpret_cast<const __half2*>(&ui.x));
            const __half2 h1 = __hadd2(*reinterpret_cast<const __half2*>(&uj.y),
                                       *reinterpret_cast<const __half2*>(&ui.y));
            const float2 f0 = __half22float2(h0);
            const float2 f1 = __half22float2(h1);
            float4 acc = make_float4(f0.x, f0.y, f1.x, f1.y);

            const float4* rb = reinterpret_cast<const float4*>(rbB + el * N_RADIAL);
#pragma unroll
            for (int q = 0; q < 4; ++q) {
                const float4 rq = rb[q];
                acc.x += rq.x * w[q * 4 + 0].x;
                acc.y += rq.x * w[q * 4 + 0].y;
                acc.z += rq.x * w[q * 4 + 0].z;
                acc.w += rq.x * w[q * 4 + 0].w;

                acc.x += rq.y * w[q * 4 + 1].x;
                acc.y += rq.y * w[q * 4 + 1].y;
                acc.z += rq.y * w[q * 4 + 1].z;
                acc.w += rq.y * w[q * 4 + 1].w;

                acc.x += rq.z * w[q * 4 + 2].x;
                acc.y += rq.z * w[q * 4 + 2].y;
                acc.z += rq.z * w[q * 4 + 2].z;
                acc.w += rq.z * w[q * 4 + 2].w;

                acc.x += rq.w * w[q * 4 + 3].x;
                acc.y += rq.w * w[q * 4 + 3].y;
                acc.z += rq.w * w[q * 4 + 3].z;
                acc.w += rq.w * w[q * 4 + 3].w;
            }

            // swish via fast rcp (rel err ~1e-6 vs threshold 0.09)
            fx4 o;
            o.x = acc.x * __builtin_amdgcn_rcpf(1.0f + __expf(-acc.x));
            o.y = acc.y * __builtin_amdgcn_rcpf(1.0f + __expf(-acc.y));
            o.z = acc.z * __builtin_amdgcn_rcpf(1.0f + __expf(-acc.z));
            o.w = acc.w * __builtin_amdgcn_rcpf(1.0f + __expf(-acc.w));

            if (e <= emax)
                *reinterpret_cast<fx4*>(
                    &out[(size_t)e * EDGE_DIM + (sub << 2)]) = o;
        }

        // ---- write staged next-chunk data into the other buffer ----
        if (hasn) {
            float* rw = rbW + (p ^ 1) * (MC * N_RADIAL);
            *reinterpret_cast<fx4*>(rw + eoff * N_RADIAL + (eqtr << 2)) = rn;
            if (lane < MC) zW[(p ^ 1) * MC + lane] = zn;
        }
    }
}

extern "C" void kernel_launch(void* const* d_in, const int* in_sizes, int n_in,
                              void* d_out, int out_size, void* d_ws, size_t ws_size,
                              hipStream_t stream) {
    const int*   zp          = (const int*)  d_in[0];
    const float* rbf         = (const float*)d_in[1];
    const int*   idx_i       = (const int*)  d_in[2];
    const int*   idx_j       = (const int*)  d_in[3];
    const float* embed_table = (const float*)d_in[4];
    const float* rbf_w       = (const float*)d_in[5];
    const float* edge_w      = (const float*)d_in[6];
    const float* edge_b      = (const float*)d_in[7];

    int max_z = in_sizes[4] / NODE_DIM;           // 100
    if (max_z > MAXZ) max_z = MAXZ;
    const int n_edges = in_sizes[2];              // 800000

    const size_t tab_bytes = (size_t)2 * MAXZ * EDGE_DIM * sizeof(__half); // 51200
    const size_t w3c_bytes = (size_t)N_RADIAL * EDGE_DIM * sizeof(float);  // 8192
    __half* tH    = (__half*)d_ws;
    float*  w3c   = (float*)((char*)d_ws + tab_bytes);
    int*    zpair = (int*)  ((char*)d_ws + tab_bytes + w3c_bytes);
    const int use_zpair =
        (ws_size >= tab_bytes + w3c_bytes + (size_t)n_edges * sizeof(int)) ? 1 : 0;
    float* out = (float*)d_out;

    precompute_tables<<<max_z + N_RADIAL, EDGE_DIM, 0, stream>>>(
        embed_table, edge_w, edge_b, rbf_w, tH, w3c, max_z);
    if (use_zpair)
        precompute_zpair<<<(n_edges + 255) / 256, 256, 0, stream>>>(
            zp, idx_i, idx_j, zpair, n_edges);

    edge_embed_kernel<<<512, BLOCK, 0, stream>>>(rbf, tH, w3c, zpair,
                                                 zp, idx_i, idx_j, use_zpair,
                                                 out, n_edges);
}